// Round 8
// baseline (18.138 us; speedup 1.0000x reference)
//
#include <hip/hip_runtime.h>
#include <math.h>

// Problem constants: N=32, CI=32, CO=32, H=64, W=64, K=2
#define NN 32
#define CI 32
#define CO 32
#define HH 64
#define WW 64
#define PLANE (HH * WW)

typedef __attribute__((ext_vector_type(8))) short bf16x8;   // MFMA A/B frag
typedef __attribute__((ext_vector_type(4))) float f32x4;    // MFMA C/D frag

// float -> bf16 (round-to-nearest-even)
__device__ inline short f2bf(float f) {
    union { float f; unsigned u; } v; v.f = f;
    unsigned r = v.u + 0x7FFFu + ((v.u >> 16) & 1u);
    return (short)(r >> 16);
}

// ---------------------------------------------------------------------------
// out[n,co,h,w] = log( sum_ci W[co,ci,par] * exp(x[n,ci,h,w]) ),
//   W = softmax(logits over ci), par = (h&1)*2 + (w&1).
//
// R7 post-mortem: MFMA structure validated (14.4us, absmax ok), but phase0
// (LDS softmax, half threads idle, 4.2M redundant exps, serial chains) +
// __syncthreads serialized against the x loads. This version is BARRIER-FREE:
//
//  - lane (l15,kb) needs only W[l15][kb*8+i] and W[l15+16][kb*8+i]; it
//    computes those 16 exps itself and gets the missing ci-sum via
//    shfl_xor(16)+shfl_xor(32) across the 4 kb-groups (same l15 = same co).
//  - logits = log(uniform(1e-6,1)) in [-13.8, 0] -> exp safe w/o max pass.
//  - x loads (the only HBM-cold traffic) issue FIRST; the whole weight
//    path (L2-hot loads, exps, shuffles) hides under their latency.
//
// Wave = parity (pr,pc); block = (image, row-pair); 1024 blocks, 4/CU.
// A-frag: row=l15 (co mod 16), k=kb*8+i. B-frag: col=l15 (px), k=kb*8+i.
// D: col=l15, row=4*kb+reg  (validated by R7's passing absmax).
// XCD swizzle: XCD k owns images 4k..4k+3 (2 MB slab) for all row-pairs.
// ---------------------------------------------------------------------------
__global__ __launch_bounds__(256, 4) void sumconv_mfma(
        const float* __restrict__ x,
        const float* __restrict__ logits,
        float* __restrict__ out) {
    const int b = blockIdx.x;                 // 0..1023
    const int n = (b & 7) * 4 + ((b >> 3) & 3);   // image (XCD-chunked)
    const int r = b >> 5;                     // row-pair 0..31

    const int t    = threadIdx.x;
    const int wave = t >> 6;                  // 0..3 = parity
    const int lane = t & 63;
    const int pr = wave >> 1, pc = wave & 1;
    const int l15 = lane & 15, kb = lane >> 4;
    const int h = 2 * r + pr;

    // ---- x loads first: 16 independent VMEM (HBM-cold) ----
    const float* xp = x + ((n * CI + kb * 8) * HH + h) * WW + 2 * l15 + pc;
    float ev0[8], ev1[8];
#pragma unroll
    for (int i = 0; i < 8; ++i) ev0[i] = xp[i * PLANE];        // px col 2*l15+pc
#pragma unroll
    for (int i = 0; i < 8; ++i) ev1[i] = xp[i * PLANE + 32];   // px col +16 tiles

    // ---- in-register softmax weights (hides under x-load flight) ----
    const float* lp0 = logits + ((l15     ) * CI + kb * 8) * 4 + wave;
    const float* lp1 = logits + ((l15 + 16) * CI + kb * 8) * 4 + wave;
    float wl0[8], wl1[8];
    float s0 = 0.f, s1 = 0.f;
#pragma unroll
    for (int i = 0; i < 8; ++i) { wl0[i] = __expf(lp0[i * 4]); s0 += wl0[i]; }
#pragma unroll
    for (int i = 0; i < 8; ++i) { wl1[i] = __expf(lp1[i * 4]); s1 += wl1[i]; }
    s0 += __shfl_xor(s0, 16); s0 += __shfl_xor(s0, 32);   // sum over kb-groups
    s1 += __shfl_xor(s1, 16); s1 += __shfl_xor(s1, 32);
    const float i0 = 1.f / s0, i1 = 1.f / s1;

    bf16x8 afr0, afr1;
#pragma unroll
    for (int i = 0; i < 8; ++i) {
        afr0[i] = f2bf(wl0[i] * i0);          // A rows co = 0..15 (row = l15)
        afr1[i] = f2bf(wl1[i] * i1);          // A rows co = 16..31
    }

    // ---- exp(x) -> bf16 B-frags ----
    bf16x8 bfr0, bfr1;
#pragma unroll
    for (int i = 0; i < 8; ++i) {
        bfr0[i] = f2bf(__expf(ev0[i]));
        bfr1[i] = f2bf(__expf(ev1[i]));
    }

    // ---- 4 MFMAs (K=32 each) ----
    const f32x4 z = {0.f, 0.f, 0.f, 0.f};
    f32x4 a00 = __builtin_amdgcn_mfma_f32_16x16x32_bf16(afr0, bfr0, z, 0, 0, 0);
    f32x4 a01 = __builtin_amdgcn_mfma_f32_16x16x32_bf16(afr0, bfr1, z, 0, 0, 0);
    f32x4 a10 = __builtin_amdgcn_mfma_f32_16x16x32_bf16(afr1, bfr0, z, 0, 0, 0);
    f32x4 a11 = __builtin_amdgcn_mfma_f32_16x16x32_bf16(afr1, bfr1, z, 0, 0, 0);

    // ---- log + store. D: col=l15 (px), row=4*kb+reg (co) ----
    const int wc0 = 2 * l15 + pc;
    float* ob = out + ((n * CO + 4 * kb) * HH + h) * WW;   // co base 4*kb
#pragma unroll
    for (int reg = 0; reg < 4; ++reg) {
        ob[(reg     ) * PLANE + wc0     ] = __logf(a00[reg]);   // co=4kb+reg
        ob[(reg     ) * PLANE + wc0 + 32] = __logf(a01[reg]);
        ob[(reg + 16) * PLANE + wc0     ] = __logf(a10[reg]);   // co=16+4kb+reg
        ob[(reg + 16) * PLANE + wc0 + 32] = __logf(a11[reg]);
    }
}

extern "C" void kernel_launch(void* const* d_in, const int* in_sizes, int n_in,
                              void* d_out, int out_size, void* d_ws, size_t ws_size,
                              hipStream_t stream) {
    const float* x      = (const float*)d_in[0];
    const float* logits = (const float*)d_in[1];
    float* out = (float*)d_out;

    sumconv_mfma<<<NN * (HH / 2), 256, 0, stream>>>(x, logits, out);
}

// Round 9
// 14.020 us; speedup vs baseline: 1.2938x; 1.2938x over previous
//
#include <hip/hip_runtime.h>
#include <math.h>

// Problem constants: N=32, CI=32, CO=32, H=64, W=64, K=2
#define NN 32
#define CI 32
#define CO 32
#define HH 64
#define WW 64
#define PLANE (HH * WW)

typedef __attribute__((ext_vector_type(8))) short bf16x8;   // MFMA A/B frag
typedef __attribute__((ext_vector_type(4))) float f32x4;    // MFMA C/D frag

// float -> bf16 (round-to-nearest-even)
__device__ inline short f2bf(float f) {
    union { float f; unsigned u; } v; v.f = f;
    unsigned r = v.u + 0x7FFFu + ((v.u >> 16) & 1u);
    return (short)(r >> 16);
}

// ---------------------------------------------------------------------------
// out[n,co,h,w] = log( sum_ci W[co,ci,par] * exp(x[n,ci,h,w]) ),
//   W = softmax(logits over ci), par = (h&1)*2 + (w&1).
//
// R8 post-mortem: VMEM weight loads issued after x-loads forced a full
// vmcnt FIFO drain (weight compute serialized behind x HBM latency).
// LDS weights use lgkmcnt -- independent counter domain. So:
//
//   1) issue the 16 HBM-cold x loads FIRST (they fly during phase 0)
//   2) phase 0: softmax -> LDS as PRE-PACKED bf16 (no max pass: logits<=0
//      bounded below by log(1e-6); softmax is shift-invariant)
//   3) barrier (vmcnt(0) drain lands at max(phase0, x flight), not sum)
//   4) A-frags = one ds_read_b128 each (no per-lane f2bf for weights)
//   5) exp(x) -> B-frags, 4 MFMAs, log, store
//
// Wave = parity (pr,pc); block = (image, row-pair); 1024 blocks, 4/CU,
// 16 waves/CU. A: row=l15+16t (co), k=kb*8+i. B: col=l15+16u (px), same k.
// D: col=l15, row=4*kb+reg (validated R7/R8 absmax).
// XCD swizzle: XCD k owns images 4k..4k+3 (2 MB x slab, L2-resident).
// ---------------------------------------------------------------------------
__global__ __launch_bounds__(256, 4) void sumconv_mfma(
        const float* __restrict__ x,
        const float* __restrict__ logits,
        float* __restrict__ out) {
    const int b = blockIdx.x;                     // 0..1023
    const int n = (b & 7) * 4 + ((b >> 3) & 3);   // image (XCD-chunked)
    const int r = b >> 5;                         // row-pair 0..31

    const int t    = threadIdx.x;
    const int wave = t >> 6;                      // 0..3 = parity
    const int lane = t & 63;
    const int pr = wave >> 1, pc = wave & 1;
    const int l15 = lane & 15, kb = lane >> 4;
    const int h = 2 * r + pr;

    __shared__ short Wl[4][CO * CI];              // bf16 weights [par][co*32+ci], 8 KB

    // ---- (1) x loads first: 16 independent HBM-cold VMEM ----
    const float* xp = x + ((n * CI + kb * 8) * HH + h) * WW + 2 * l15 + pc;
    float ev0[8], ev1[8];
#pragma unroll
    for (int i = 0; i < 8; ++i) ev0[i] = xp[i * PLANE];        // px cols 0..31
#pragma unroll
    for (int i = 0; i < 8; ++i) ev1[i] = xp[i * PLANE + 32];   // px cols 32..63

    // ---- (2) phase 0: softmax -> LDS bf16 (128 active threads) ----
    if (t < 128) {
        const int co = t >> 2, par = t & 3;
        const float* base = logits + (co * CI) * 4 + par;
        float e[CI];
        float ssum = 0.0f;
#pragma unroll
        for (int ci = 0; ci < CI; ++ci) { e[ci] = __expf(base[ci * 4]); ssum += e[ci]; }
        const float inv = 1.0f / ssum;
#pragma unroll
        for (int ci = 0; ci < CI; ++ci) Wl[par][co * CI + ci] = f2bf(e[ci] * inv);
    }
    __syncthreads();

    // ---- (4) A-frags: one aligned ds_read_b128 per co-half ----
    const bf16x8 afr0 = *(const bf16x8*)&Wl[wave][(l15     ) * CI + kb * 8];
    const bf16x8 afr1 = *(const bf16x8*)&Wl[wave][(l15 + 16) * CI + kb * 8];

    // ---- (5) exp(x) -> bf16 B-frags (x landed during phase 0) ----
    bf16x8 bfr0, bfr1;
#pragma unroll
    for (int i = 0; i < 8; ++i) {
        bfr0[i] = f2bf(__expf(ev0[i]));
        bfr1[i] = f2bf(__expf(ev1[i]));
    }

    // ---- 4 MFMAs (K=32 each) ----
    const f32x4 z = {0.f, 0.f, 0.f, 0.f};
    f32x4 a00 = __builtin_amdgcn_mfma_f32_16x16x32_bf16(afr0, bfr0, z, 0, 0, 0);
    f32x4 a01 = __builtin_amdgcn_mfma_f32_16x16x32_bf16(afr0, bfr1, z, 0, 0, 0);
    f32x4 a10 = __builtin_amdgcn_mfma_f32_16x16x32_bf16(afr1, bfr0, z, 0, 0, 0);
    f32x4 a11 = __builtin_amdgcn_mfma_f32_16x16x32_bf16(afr1, bfr1, z, 0, 0, 0);

    // ---- log + store. D: col=l15 (px), row=4*kb+reg (co) ----
    const int wc0 = 2 * l15 + pc;
    float* ob = out + ((n * CO + 4 * kb) * HH + h) * WW;      // co base 4*kb
#pragma unroll
    for (int reg = 0; reg < 4; ++reg) {
        ob[(reg     ) * PLANE + wc0     ] = __logf(a00[reg]);   // co = 4kb+reg
        ob[(reg     ) * PLANE + wc0 + 32] = __logf(a01[reg]);
        ob[(reg + 16) * PLANE + wc0     ] = __logf(a10[reg]);   // co = 16+4kb+reg
        ob[(reg + 16) * PLANE + wc0 + 32] = __logf(a11[reg]);
    }
}

extern "C" void kernel_launch(void* const* d_in, const int* in_sizes, int n_in,
                              void* d_out, int out_size, void* d_ws, size_t ws_size,
                              hipStream_t stream) {
    const float* x      = (const float*)d_in[0];
    const float* logits = (const float*)d_in[1];
    float* out = (float*)d_out;

    sumconv_mfma<<<NN * (HH / 2), 256, 0, stream>>>(x, logits, out);
}